// Round 8
// baseline (577.172 us; speedup 1.0000x reference)
//
#include <hip/hip_runtime.h>

// TextEncoder on MI355X gfx950. fp32 globals, bf16 internals, fp32 accum MFMA.
// R8: flash uses register-staged double-buffered K/V (global->VGPR->ds_write,
// vm-wait overlapped by compute; barrier only drains lgkm) instead of
// global_load_lds prefetch whose barrier drained vmcnt(0) every iteration.
// QKV GEMM widened to 128x128. Split-K + fused combine+LN kept from R7.

typedef unsigned short u16;
typedef __bf16 v8bf __attribute__((ext_vector_type(8)));
typedef float  v4f  __attribute__((ext_vector_type(4)));

constexpr int Bx = 4, Lx = 1024, Cx = 512, Hx = 8, Dx = 64, FCx = 2048, NLx = 4, WX = 4;
constexpr int C3 = 3 * Cx;
constexpr int BL_ = Bx * Lx;              // 4096 tokens
constexpr float SCALEx = 0.125f;
constexpr float EPSx = 1e-6f;

__device__ __forceinline__ float b2f(u16 u) {
    unsigned x = ((unsigned)u) << 16;
    return __builtin_bit_cast(float, x);
}
__device__ __forceinline__ u16 f2b(float f) {   // RNE bf16
    unsigned x = __builtin_bit_cast(unsigned, f);
    x += 0x7fffu + ((x >> 16) & 1u);
    return (u16)(x >> 16);
}
__device__ __forceinline__ float ldf(const float* p) { return *p; }
__device__ __forceinline__ float ldf(const u16* p)   { return b2f(*p); }
__device__ __forceinline__ void  stf(float* p, float v) { *p = v; }
__device__ __forceinline__ void  stf(u16* p, float v)   { *p = f2b(v); }

__device__ __forceinline__ void async16(const u16* gsrc, u16* ldst) {
    __builtin_amdgcn_global_load_lds(
        (const __attribute__((address_space(1))) unsigned int*)gsrc,
        (__attribute__((address_space(3))) unsigned int*)ldst, 16, 0, 0);
}

// Stage ROWS x 64 bf16 tile into LDS (contiguous 128B rows). Physical slot s of
// row r holds GLOBAL granule s^(r&7). All lanes active, dest=base+lane*16.
template<int ROWS>
__device__ __forceinline__ void stage_sw(const u16* gbase, long rstride,
                                         u16* lds, int tid)
{
#pragma unroll
    for (int i = 0; i < ROWS * 8 / 256; i++) {
        int g = tid + i * 256;
        int r = g >> 3, s = g & 7;
        int sc = s ^ (r & 7);
        async16(gbase + (long)r * rstride + sc * 8, lds + g * 8);
    }
}
__device__ __forceinline__ int swaddr(int row, int g0) {
    return row * 64 + ((g0 ^ (row & 7)) << 3);
}

// ---- weight packing ----
__global__ __launch_bounds__(256)
void pack_w(const float* __restrict__ src, u16* __restrict__ dst,
            int per_layer, long dst_lstride, float scale, int total)
{
    for (int i = blockIdx.x * 256 + threadIdx.x; i < total; i += gridDim.x * 256) {
        int l = i / per_layer, o = i % per_layer;
        dst[(long)l * dst_lstride + o] = f2b(src[i] * scale);
    }
}
__global__ __launch_bounds__(256)
void pack_f(const float* __restrict__ src, float* __restrict__ dst,
            int per_layer, long dst_lstride, float scale, int total)
{
    for (int i = blockIdx.x * 256 + threadIdx.x; i < total; i += gridDim.x * 256) {
        int l = i / per_layer, o = i % per_layer;
        dst[(long)l * dst_lstride + o] = src[i] * scale;
    }
}

// ---- GEMM-BT with bf16 epilogue (bias, optional relu) ----
template<int BM, int BN>
__global__ __launch_bounds__(256, 2)
void gemm_bt(const u16* __restrict__ A, const u16* __restrict__ Bw,
             u16* __restrict__ Cm, const float* __restrict__ bias,
             int K, int lda, int ldb, int ldc, int relu)
{
    __shared__ __align__(16) u16 As[BM * 64];
    __shared__ __align__(16) u16 Bs[BN * 64];

    const int tid  = threadIdx.x;
    const int m0   = blockIdx.y * BM;
    const int n0   = blockIdx.x * BN;
    const int lane = tid & 63;
    const int wid  = tid >> 6;
    const int wm   = (wid >> 1) * (BM / 2);
    const int wn   = (wid & 1)  * (BN / 2);
    const int lrow = lane & 15;
    const int quad = lane >> 4;

    constexpr int WTM = BM / 32, WTN = BN / 32;
    v4f acc[WTM][WTN];
#pragma unroll
    for (int a = 0; a < WTM; a++)
#pragma unroll
        for (int b = 0; b < WTN; b++) acc[a][b] = v4f{0.f, 0.f, 0.f, 0.f};

    for (int k0 = 0; k0 < K; k0 += 64) {
        stage_sw<BM>(A + (long)m0 * lda + k0, lda, As, tid);
        stage_sw<BN>(Bw + (long)n0 * ldb + k0, ldb, Bs, tid);
        __syncthreads();
#pragma unroll
        for (int ki = 0; ki < 2; ki++) {
            v8bf af[WTM], bfr[WTN];
#pragma unroll
            for (int mi = 0; mi < WTM; mi++)
                af[mi] = *reinterpret_cast<const v8bf*>(&As[swaddr(wm + mi * 16 + lrow, ki * 4 + quad)]);
#pragma unroll
            for (int ni = 0; ni < WTN; ni++)
                bfr[ni] = *reinterpret_cast<const v8bf*>(&Bs[swaddr(wn + ni * 16 + lrow, ki * 4 + quad)]);
#pragma unroll
            for (int mi = 0; mi < WTM; mi++)
#pragma unroll
                for (int ni = 0; ni < WTN; ni++)
                    acc[mi][ni] = __builtin_amdgcn_mfma_f32_16x16x32_bf16(
                        af[mi], bfr[ni], acc[mi][ni], 0, 0, 0);
        }
        __syncthreads();
    }

#pragma unroll
    for (int mi = 0; mi < WTM; mi++)
#pragma unroll
        for (int ni = 0; ni < WTN; ni++) {
            const int col = n0 + wn + ni * 16 + lrow;
            const float bv = bias[col];
#pragma unroll
            for (int r = 0; r < 4; r++) {
                const int row = m0 + wm + mi * 16 + quad * 4 + r;
                float v = acc[mi][ni][r] + bv;
                if (relu) v = fmaxf(v, 0.f);
                Cm[(long)row * ldc + col] = f2b(v);
            }
        }
}

// ---- split-K GEMM-BT: fp32 partials, no epilogue. N=512, M=4096 fixed. ----
template<int BM, int BN>
__global__ __launch_bounds__(256, 2)
void gemm_sk(const u16* __restrict__ A, const u16* __restrict__ Bw,
             float* __restrict__ Pp, int lda, int ldb, int kslice)
{
    __shared__ __align__(16) u16 As[BM * 64];
    __shared__ __align__(16) u16 Bs[BN * 64];

    const int tid  = threadIdx.x;
    const int m0   = blockIdx.y * BM;
    const int n0   = blockIdx.x * BN;
    const int z    = blockIdx.z;
    const int lane = tid & 63;
    const int wid  = tid >> 6;
    const int wm   = (wid >> 1) * (BM / 2);
    const int wn   = (wid & 1)  * (BN / 2);
    const int lrow = lane & 15;
    const int quad = lane >> 4;

    constexpr int WTM = BM / 32, WTN = BN / 32;
    v4f acc[WTM][WTN];
#pragma unroll
    for (int a = 0; a < WTM; a++)
#pragma unroll
        for (int b = 0; b < WTN; b++) acc[a][b] = v4f{0.f, 0.f, 0.f, 0.f};

    const int kend = (z + 1) * kslice;
    for (int k0 = z * kslice; k0 < kend; k0 += 64) {
        stage_sw<BM>(A + (long)m0 * lda + k0, lda, As, tid);
        stage_sw<BN>(Bw + (long)n0 * ldb + k0, ldb, Bs, tid);
        __syncthreads();
#pragma unroll
        for (int ki = 0; ki < 2; ki++) {
            v8bf af[WTM], bfr[WTN];
#pragma unroll
            for (int mi = 0; mi < WTM; mi++)
                af[mi] = *reinterpret_cast<const v8bf*>(&As[swaddr(wm + mi * 16 + lrow, ki * 4 + quad)]);
#pragma unroll
            for (int ni = 0; ni < WTN; ni++)
                bfr[ni] = *reinterpret_cast<const v8bf*>(&Bs[swaddr(wn + ni * 16 + lrow, ki * 4 + quad)]);
#pragma unroll
            for (int mi = 0; mi < WTM; mi++)
#pragma unroll
                for (int ni = 0; ni < WTN; ni++)
                    acc[mi][ni] = __builtin_amdgcn_mfma_f32_16x16x32_bf16(
                        af[mi], bfr[ni], acc[mi][ni], 0, 0, 0);
        }
        __syncthreads();
    }

    float* Pz = Pp + (long)z * BL_ * Cx;
#pragma unroll
    for (int mi = 0; mi < WTM; mi++)
#pragma unroll
        for (int ni = 0; ni < WTN; ni++) {
            const int col = n0 + wn + ni * 16 + lrow;
#pragma unroll
            for (int r = 0; r < 4; r++) {
                const int row = m0 + wm + mi * 16 + quad * 4 + r;
                Pz[(long)row * Cx + col] = acc[mi][ni][r];
            }
        }
}

// ---- combine split-K partials + bias + residual, then LayerNorm ----
template<int SK>
__global__ __launch_bounds__(256)
void combine_ln(const float* __restrict__ Pp, const float* __restrict__ bias,
                const u16* __restrict__ res, u16* __restrict__ outp,
                const float* __restrict__ gg, const float* __restrict__ bb)
{
    const int wid = threadIdx.x >> 6, lane = threadIdx.x & 63;
    const long r = (long)blockIdx.x * 4 + wid;
    const int c0 = lane * 8;

    int4 t = *reinterpret_cast<const int4*>(res + r * Cx + c0);
    const u16* u = reinterpret_cast<const u16*>(&t);
    float x[8];
#pragma unroll
    for (int i = 0; i < 8; i++) x[i] = b2f(u[i]) + bias[c0 + i];
#pragma unroll
    for (int s = 0; s < SK; s++) {
        const float* p = Pp + ((long)s * BL_ + r) * Cx + c0;
        float4 a = *reinterpret_cast<const float4*>(p);
        float4 b = *reinterpret_cast<const float4*>(p + 4);
        x[0] += a.x; x[1] += a.y; x[2] += a.z; x[3] += a.w;
        x[4] += b.x; x[5] += b.y; x[6] += b.z; x[7] += b.w;
    }
    float s1 = 0.f, s2 = 0.f;
#pragma unroll
    for (int i = 0; i < 8; i++) { s1 += x[i]; s2 += x[i] * x[i]; }
#pragma unroll
    for (int o = 32; o > 0; o >>= 1) { s1 += __shfl_xor(s1, o, 64); s2 += __shfl_xor(s2, o, 64); }
    const float mu = s1 * (1.f / Cx);
    const float var = s2 * (1.f / Cx) - mu * mu;
    const float rs = rsqrtf(var + EPSx);
    int4 ot; u16* ou = reinterpret_cast<u16*>(&ot);
#pragma unroll
    for (int i = 0; i < 8; i++)
        ou[i] = f2b((x[i] - mu) * rs * gg[c0 + i] + bb[c0 + i]);
    *reinterpret_cast<int4*>(outp + r * Cx + c0) = ot;
}

// ---- flash attention: no-max softmax, register-staged dbuf K/V ----
__global__ __launch_bounds__(256, 2)
void flash_attn(const u16* __restrict__ qkv, const u16* __restrict__ vt,
                const float* __restrict__ relk, const float* __restrict__ relv,
                u16* __restrict__ ao)
{
    const int bh = blockIdx.y, b = bh >> 3, h = bh & 7;
    const int q0 = blockIdx.x * 64;
    const int tid = threadIdx.x, lane = tid & 63, w = tid >> 6;
    const int lrow = lane & 15, quad = lane >> 4;
    constexpr int NT = Lx / 64;

    __shared__ __align__(16) u16 Qs[64 * 64];
    __shared__ __align__(16) u16 Ks[2][64 * 64];
    __shared__ __align__(16) u16 Vs[2][64 * 64];
    __shared__ __align__(16) u16 Ps[4][16 * 64];
    __shared__ float rbias[64][9];
    __shared__ float swin[4][16][9];

    const u16* qbase = qkv + (long)b * Lx * C3 + h * Dx;
    const u16* kbase = qbase + Cx;
    const u16* vbase = vt + (long)bh * Dx * Lx;

    // initial tiles via async LDS DMA (one-time; barrier drain acceptable here)
    stage_sw<64>(qbase + (long)q0 * C3, C3, Qs, tid);
    stage_sw<64>(kbase, C3, Ks[0], tid);
    stage_sw<64>(vbase, Lx, Vs[0], tid);
    for (int i = tid; i < 4 * 16 * 9; i += 256) (&swin[0][0][0])[i] = -1e30f;
    __syncthreads();

    for (int i = tid; i < 64 * 9; i += 256) {
        int r = i / 9, j = i - (i / 9) * 9;
        float d = 0.f;
        for (int dd = 0; dd < 64; dd++)
            d += b2f(Qs[r * 64 + (((dd >> 3) ^ (r & 7)) << 3) + (dd & 7)]) * relk[j * 64 + dd];
        rbias[r][j] = d;
    }
    __syncthreads();

    // precompute this thread's staging coordinates (swizzled)
    int srow[2], scol[2];
#pragma unroll
    for (int i = 0; i < 2; i++) {
        int g = tid + i * 256;
        srow[i] = g >> 3;
        scol[i] = ((g & 7) ^ (srow[i] & 7)) * 8;
    }

    v4f out[4], sfr[4];
    float lpart[4] = {0.f, 0.f, 0.f, 0.f};
#pragma unroll
    for (int nt = 0; nt < 4; nt++) out[nt] = v4f{0.f, 0.f, 0.f, 0.f};

    v8bf aq0 = *reinterpret_cast<const v8bf*>(&Qs[swaddr(w * 16 + lrow, quad)]);
    v8bf aq1 = *reinterpret_cast<const v8bf*>(&Qs[swaddr(w * 16 + lrow, 4 + quad)]);
    const int qw0 = q0 + w * 16;

    for (int kt = 0; kt < NT; kt++) {
        const int k0 = kt * 64;
        const int cur = kt & 1;

        // register prefetch of next K/V tile (vm-wait deferred to ds_write below)
        int4 pk[2], pv[2];
        if (kt < NT - 1) {
            const u16* kb2 = kbase + (long)(k0 + 64) * C3;
            const u16* vb2 = vbase + (k0 + 64);
#pragma unroll
            for (int i = 0; i < 2; i++) {
                pk[i] = *reinterpret_cast<const int4*>(kb2 + (long)srow[i] * C3 + scol[i]);
                pv[i] = *reinterpret_cast<const int4*>(vb2 + (long)srow[i] * Lx + scol[i]);
            }
        }

        v8bf bk[2][4], bv[2][4];
#pragma unroll
        for (int ki = 0; ki < 2; ki++)
#pragma unroll
            for (int nt = 0; nt < 4; nt++) {
                bk[ki][nt] = *reinterpret_cast<const v8bf*>(&Ks[cur][swaddr(nt * 16 + lrow, ki * 4 + quad)]);
                bv[ki][nt] = *reinterpret_cast<const v8bf*>(&Vs[cur][swaddr(nt * 16 + lrow, ki * 4 + quad)]);
            }

#pragma unroll
        for (int nt = 0; nt < 4; nt++) sfr[nt] = v4f{0.f, 0.f, 0.f, 0.f};
#pragma unroll
        for (int ki = 0; ki < 2; ki++)
#pragma unroll
            for (int nt = 0; nt < 4; nt++)
                sfr[nt] = __builtin_amdgcn_mfma_f32_16x16x32_bf16(
                    ki ? aq1 : aq0, bk[ki][nt], sfr[nt], 0, 0, 0);

        if (k0 <= qw0 + 15 + WX && k0 + 63 >= qw0 - WX) {   // wave-uniform guard
#pragma unroll
            for (int nt = 0; nt < 4; nt++) {
                const int m = k0 + nt * 16 + lrow;
#pragma unroll
                for (int r = 0; r < 4; r++) {
                    const int dj = m - (qw0 + quad * 4 + r);
                    if (dj >= -WX && dj <= WX) {
                        float sv = sfr[nt][r] + rbias[w * 16 + quad * 4 + r][dj + WX];
                        sfr[nt][r] = sv;
                        swin[w][quad * 4 + r][dj + WX] = sv;
                    }
                }
            }
        }

#pragma unroll
        for (int nt = 0; nt < 4; nt++)
#pragma unroll
            for (int r = 0; r < 4; r++) {
                float p = __expf(sfr[nt][r]);
                sfr[nt][r] = p;
                lpart[r] += p;
            }

        // P: C-layout -> swizzled wave-private LDS -> A-layout
#pragma unroll
        for (int nt = 0; nt < 4; nt++)
#pragma unroll
            for (int r = 0; r < 4; r++) {
                const int prow = quad * 4 + r;
                Ps[w][prow * 64 + (((nt * 2 + (lrow >> 3)) ^ (prow & 7)) << 3) + (lrow & 7)]
                    = f2b(sfr[nt][r]);
            }

        v8bf pa0 = *reinterpret_cast<const v8bf*>(&Ps[w][swaddr(lrow, quad)]);
        v8bf pa1 = *reinterpret_cast<const v8bf*>(&Ps[w][swaddr(lrow, 4 + quad)]);
#pragma unroll
        for (int nt = 0; nt < 4; nt++) {
            out[nt] = __builtin_amdgcn_mfma_f32_16x16x32_bf16(pa0, bv[0][nt], out[nt], 0, 0, 0);
            out[nt] = __builtin_amdgcn_mfma_f32_16x16x32_bf16(pa1, bv[1][nt], out[nt], 0, 0, 0);
        }

        // commit prefetched tile to the other LDS buffer, then one barrier
        if (kt < NT - 1) {
            u16* Kn = Ks[cur ^ 1];
            u16* Vn = Vs[cur ^ 1];
#pragma unroll
            for (int i = 0; i < 2; i++) {
                *reinterpret_cast<int4*>(Kn + (tid + i * 256) * 8) = pk[i];
                *reinterpret_cast<int4*>(Vn + (tid + i * 256) * 8) = pv[i];
            }
        }
        __syncthreads();
    }

#pragma unroll
    for (int off = 1; off < 16; off <<= 1)
#pragma unroll
        for (int r = 0; r < 4; r++) lpart[r] += __shfl_xor(lpart[r], off, 64);
    float inv[4];
#pragma unroll
    for (int r = 0; r < 4; r++) inv[r] = 1.f / lpart[r];

    float e[4][9];
#pragma unroll
    for (int r = 0; r < 4; r++)
#pragma unroll
        for (int j = 0; j < 9; j++) e[r][j] = __expf(swin[w][quad * 4 + r][j]);
#pragma unroll
    for (int nt = 0; nt < 4; nt++) {
        const int d = nt * 16 + lrow;
#pragma unroll
        for (int r = 0; r < 4; r++) {
            float a = out[nt][r];
#pragma unroll
            for (int j = 0; j < 9; j++) a += e[r][j] * relv[j * 64 + d];
            ao[((long)(b * Lx + qw0 + quad * 4 + r)) * Cx + h * Dx + d] = f2b(a * inv[r]);
        }
    }
}

// ---- transpose with dtype conversion ----
template<typename TI, typename TO>
__global__ __launch_bounds__(256)
void transpose_k(const TI* __restrict__ in, TO* __restrict__ outp,
                 int ld_in, int ld_out, int zdiv,
                 long si1, long si2, long so1, long so2)
{
    const int z = blockIdx.z;
    in   += (z / zdiv) * si1 + (z % zdiv) * si2;
    outp += (z / zdiv) * so1 + (z % zdiv) * so2;
    const int r0 = blockIdx.y * 32, c0 = blockIdx.x * 32;
    __shared__ float t[32][33];
    const int tid = threadIdx.x;
    const int lr = tid >> 3, lc = (tid & 7) * 4;
#pragma unroll
    for (int j = 0; j < 4; j++)
        t[lr][lc + j] = ldf(in + (long)(r0 + lr) * ld_in + (c0 + lc + j));
    __syncthreads();
#pragma unroll
    for (int j = 0; j < 4; j++)
        stf(outp + (long)(c0 + lr) * ld_out + (r0 + lc + j), t[lc + j][lr]);
}

extern "C" void kernel_launch(void* const* d_in, const int* in_sizes, int n_in,
                              void* d_out, int out_size, void* d_ws, size_t ws_size,
                              hipStream_t stream)
{
    const float* x   = (const float*)d_in[0];
    const float* wq  = (const float*)d_in[2];
    const float* bq  = (const float*)d_in[3];
    const float* wk  = (const float*)d_in[4];
    const float* bk  = (const float*)d_in[5];
    const float* wv  = (const float*)d_in[6];
    const float* bv  = (const float*)d_in[7];
    const float* wo  = (const float*)d_in[8];
    const float* bo  = (const float*)d_in[9];
    const float* rk  = (const float*)d_in[10];
    const float* rv  = (const float*)d_in[11];
    const float* l1g = (const float*)d_in[12];
    const float* l1b = (const float*)d_in[13];
    const float* w1  = (const float*)d_in[14];
    const float* b1  = (const float*)d_in[15];
    const float* w2  = (const float*)d_in[16];
    const float* b2  = (const float*)d_in[17];
    const float* l2g = (const float*)d_in[18];
    const float* l2b = (const float*)d_in[19];
    float* out = (float*)d_out;

    const long BL = (long)BL_;
    char* wp = (char*)d_ws;
    auto carveB = [&](long bytes) -> char* {
        char* p = wp;
        wp += ((bytes + 255) & ~255L);
        return p;
    };
    u16* xt    = (u16*)carveB(BL * Cx * 2);
    u16* qkv   = (u16*)carveB(BL * C3 * 2);
    u16* vt    = (u16*)carveB(BL * Cx * 2);
    u16* ao    = (u16*)carveB(BL * Cx * 2);
    u16* x2    = (u16*)carveB(BL * Cx * 2);
    u16* h1    = (u16*)carveB(BL * FCx * 2);
    u16* wqkvb = (u16*)carveB((long)NLx * C3 * Cx * 2);
    u16* wob   = (u16*)carveB((long)NLx * Cx * Cx * 2);
    u16* w1b   = (u16*)carveB((long)NLx * FCx * Cx * 2);
    u16* w2b   = (u16*)carveB((long)NLx * Cx * FCx * 2);
    float* bqkvf = (float*)carveB((long)NLx * C3 * 4);
    float* pp    = (float*)carveB((long)4 * BL * Cx * 4);   // 32 MB split-K partials

    const int CC = Cx * Cx;
    const long WL = (long)C3 * Cx;
    pack_w<<<1024, 256, 0, stream>>>(wq, wqkvb,          CC, WL, SCALEx, NLx * CC);
    pack_w<<<1024, 256, 0, stream>>>(wk, wqkvb + CC,     CC, WL, 1.f,    NLx * CC);
    pack_w<<<1024, 256, 0, stream>>>(wv, wqkvb + 2 * CC, CC, WL, 1.f,    NLx * CC);
    pack_w<<<1024, 256, 0, stream>>>(wo, wob, NLx * CC, NLx * CC, 1.f,   NLx * CC);
    pack_w<<<2048, 256, 0, stream>>>(w1, w1b, NLx * FCx * Cx, (long)NLx * FCx * Cx, 1.f, NLx * FCx * Cx);
    pack_w<<<2048, 256, 0, stream>>>(w2, w2b, NLx * FCx * Cx, (long)NLx * FCx * Cx, 1.f, NLx * FCx * Cx);
    pack_f<<<8, 256, 0, stream>>>(bq, bqkvf,          Cx, C3, SCALEx, NLx * Cx);
    pack_f<<<8, 256, 0, stream>>>(bk, bqkvf + Cx,     Cx, C3, 1.f,    NLx * Cx);
    pack_f<<<8, 256, 0, stream>>>(bv, bqkvf + 2 * Cx, Cx, C3, 1.f,    NLx * Cx);

    transpose_k<float, u16><<<dim3(Lx / 32, Cx / 32, Bx), 256, 0, stream>>>(
        x, xt, Lx, Cx, 1, (long)Cx * Lx, 0, (long)Lx * Cx, 0);

    for (int i = 0; i < NLx; i++) {
        const u16* wqkvi = wqkvb + (long)i * WL;
        const u16* woi   = wob + (long)i * CC;
        const u16* w1i   = w1b + (long)i * FCx * Cx;
        const u16* w2i   = w2b + (long)i * Cx * FCx;
        const float* bqkvi = bqkvf + (long)i * C3;

        // fused QKV projection (128x128 tiles, 384 blocks)
        gemm_bt<128, 128><<<dim3(C3 / 128, BL_ / 128), 256, 0, stream>>>(
            xt, wqkvi, qkv, bqkvi, Cx, Cx, Cx, C3, 0);

        transpose_k<u16, u16><<<dim3(Dx / 32, Lx / 32, Bx * Hx), 256, 0, stream>>>(
            qkv + 2 * Cx, vt, C3, Lx, Hx, (long)Lx * C3, Dx, (long)Hx * Dx * Lx, (long)Dx * Lx);

        flash_attn<<<dim3(Lx / 64, Bx * Hx), 256, 0, stream>>>(
            qkv, vt, rk + i * 9 * Dx, rv + i * 9 * Dx, ao);

        // O-projection: split-K=2, then combine + bias + residual(xt) + LN -> x2
        gemm_sk<128, 128><<<dim3(Cx / 128, BL_ / 128, 2), 256, 0, stream>>>(
            ao, woi, pp, Cx, Cx, Cx / 2);
        combine_ln<2><<<dim3(BL_ / 4), 256, 0, stream>>>(
            pp, bo + i * Cx, xt, x2, l1g + i * Cx, l1b + i * Cx);

        // FFN1 (bias+relu)
        gemm_bt<128, 128><<<dim3(FCx / 128, BL_ / 128), 256, 0, stream>>>(
            x2, w1i, h1, b1 + i * FCx, Cx, Cx, Cx, FCx, 1);

        // FFN2: split-K=4, combine + bias + residual(x2) + LN -> xt
        gemm_sk<128, 128><<<dim3(Cx / 128, BL_ / 128, 4), 256, 0, stream>>>(
            h1, w2i, pp, FCx, FCx, FCx / 4);
        combine_ln<4><<<dim3(BL_ / 4), 256, 0, stream>>>(
            pp, b2 + i * Cx, x2, xt, l2g + i * Cx, l2b + i * Cx);
    }

    transpose_k<u16, float><<<dim3(Cx / 32, Lx / 32, Bx), 256, 0, stream>>>(
        xt, out, Cx, Lx, 1, (long)Lx * Cx, 0, (long)Cx * Lx, 0);
}

// Round 9
// 564.456 us; speedup vs baseline: 1.0225x; 1.0225x over previous
//
#include <hip/hip_runtime.h>

// TextEncoder on MI355X gfx950. fp32 globals, bf16 internals, fp32 accum MFMA.
// R9: GEMMs use mfma_f32_32x32x16_bf16 (16 MFMA issues/wave/K-tile instead of
// 32 at same ds_read count; ubench +15%). All weight/bias packing merged into
// ONE grid-stride kernel. Flash kept from R8 (reg-staged dbuf, neutral-proven).

typedef unsigned short u16;
typedef __bf16 v8bf __attribute__((ext_vector_type(8)));
typedef float  v4f  __attribute__((ext_vector_type(4)));
typedef float  v16f __attribute__((ext_vector_type(16)));

constexpr int Bx = 4, Lx = 1024, Cx = 512, Hx = 8, Dx = 64, FCx = 2048, NLx = 4, WX = 4;
constexpr int C3 = 3 * Cx;
constexpr int BL_ = Bx * Lx;              // 4096 tokens
constexpr float SCALEx = 0.125f;
constexpr float EPSx = 1e-6f;

__device__ __forceinline__ float b2f(u16 u) {
    unsigned x = ((unsigned)u) << 16;
    return __builtin_bit_cast(float, x);
}
__device__ __forceinline__ u16 f2b(float f) {   // RNE bf16
    unsigned x = __builtin_bit_cast(unsigned, f);
    x += 0x7fffu + ((x >> 16) & 1u);
    return (u16)(x >> 16);
}
__device__ __forceinline__ float ldf(const float* p) { return *p; }
__device__ __forceinline__ float ldf(const u16* p)   { return b2f(*p); }
__device__ __forceinline__ void  stf(float* p, float v) { *p = v; }
__device__ __forceinline__ void  stf(u16* p, float v)   { *p = f2b(v); }

__device__ __forceinline__ void async16(const u16* gsrc, u16* ldst) {
    __builtin_amdgcn_global_load_lds(
        (const __attribute__((address_space(1))) unsigned int*)gsrc,
        (__attribute__((address_space(3))) unsigned int*)ldst, 16, 0, 0);
}

// Stage ROWS x 64 bf16 tile into LDS (contiguous 128B rows). Physical slot s of
// row r holds GLOBAL granule s^(r&7). All lanes active, dest=base+lane*16.
template<int ROWS>
__device__ __forceinline__ void stage_sw(const u16* gbase, long rstride,
                                         u16* lds, int tid)
{
#pragma unroll
    for (int i = 0; i < ROWS * 8 / 256; i++) {
        int g = tid + i * 256;
        int r = g >> 3, s = g & 7;
        int sc = s ^ (r & 7);
        async16(gbase + (long)r * rstride + sc * 8, lds + g * 8);
    }
}
__device__ __forceinline__ int swaddr(int row, int g0) {
    return row * 64 + ((g0 ^ (row & 7)) << 3);
}

// ---- single merged packing kernel (all segments are pow2-sized) ----
// layout: [3x1048576 qkv-w][1048576 wo][4194304 w1][4194304 w2][3x2048 qkv-b]
__global__ __launch_bounds__(256)
void pack_all(const float* __restrict__ wq, const float* __restrict__ wk,
              const float* __restrict__ wv, const float* __restrict__ wo,
              const float* __restrict__ w1, const float* __restrict__ w2,
              const float* __restrict__ bq, const float* __restrict__ bk,
              const float* __restrict__ bv,
              u16* __restrict__ wqkvb, u16* __restrict__ wob,
              u16* __restrict__ w1b, u16* __restrict__ w2b,
              float* __restrict__ bqkvf)
{
    const int CC = Cx * Cx;                       // 262144
    const long WL = (long)C3 * Cx;                // 786432
    const int total = 3 * NLx * CC + NLx * CC + 2 * NLx * FCx * Cx + 3 * NLx * Cx;
    for (int idx = blockIdx.x * 256 + threadIdx.x; idx < total; idx += gridDim.x * 256) {
        int i = idx;
        if (i < 3 * NLx * CC) {                   // fused qkv weights
            int which = i >> 20;                  // /1048576
            int rem = i & (NLx * CC - 1);
            int l = rem >> 18, o = rem & (CC - 1);
            const float* src = which == 0 ? wq : (which == 1 ? wk : wv);
            float sc = which == 0 ? SCALEx : 1.f;
            wqkvb[(long)l * WL + which * CC + o] = f2b(src[l * CC + o] * sc);
            continue;
        }
        i -= 3 * NLx * CC;
        if (i < NLx * CC) { wob[i] = f2b(wo[i]); continue; }
        i -= NLx * CC;
        if (i < NLx * FCx * Cx) { w1b[i] = f2b(w1[i]); continue; }
        i -= NLx * FCx * Cx;
        if (i < NLx * FCx * Cx) { w2b[i] = f2b(w2[i]); continue; }
        i -= NLx * FCx * Cx;
        {                                          // fused qkv bias (fp32)
            int which = i >> 11;                  // /2048
            int rem = i & (NLx * Cx - 1);
            int l = rem >> 9, o = rem & (Cx - 1);
            const float* src = which == 0 ? bq : (which == 1 ? bk : bv);
            float sc = which == 0 ? SCALEx : 1.f;
            bqkvf[l * C3 + which * Cx + o] = src[l * Cx + o] * sc;
        }
    }
}

// ---- 32x32x16-MFMA K-loop shared by both GEMM variants ----
// wave covers 64x64: 2x2 tiles of 32x32. acc[4] = {mi0ni0, mi0ni1, mi1ni0, mi1ni1}.
template<int BM, int BN>
__device__ __forceinline__ void kloop_3232(
    const u16* A, const u16* Bw, int K, int lda, int ldb,
    u16* As, u16* Bs, int tid, int m0, int n0, int wm, int wn,
    int l31, int half, v16f acc[4])
{
    for (int k0 = 0; k0 < K; k0 += 64) {
        stage_sw<BM>(A + (long)m0 * lda + k0, lda, As, tid);
        stage_sw<BN>(Bw + (long)n0 * ldb + k0, ldb, Bs, tid);
        __syncthreads();
#pragma unroll
        for (int ks = 0; ks < 4; ks++) {
            const int g0 = ks * 2 + half;
            v8bf af[2], bfr[2];
#pragma unroll
            for (int mi = 0; mi < 2; mi++)
                af[mi] = *reinterpret_cast<const v8bf*>(&As[swaddr(wm + mi * 32 + l31, g0)]);
#pragma unroll
            for (int ni = 0; ni < 2; ni++)
                bfr[ni] = *reinterpret_cast<const v8bf*>(&Bs[swaddr(wn + ni * 32 + l31, g0)]);
#pragma unroll
            for (int mi = 0; mi < 2; mi++)
#pragma unroll
                for (int ni = 0; ni < 2; ni++)
                    acc[mi * 2 + ni] = __builtin_amdgcn_mfma_f32_32x32x16_bf16(
                        af[mi], bfr[ni], acc[mi * 2 + ni], 0, 0, 0);
        }
        __syncthreads();
    }
}

// ---- GEMM-BT (bf16 out, bias, optional relu), 32x32 MFMA ----
template<int BM, int BN>
__global__ __launch_bounds__(256, 2)
void gemm_bt(const u16* __restrict__ A, const u16* __restrict__ Bw,
             u16* __restrict__ Cm, const float* __restrict__ bias,
             int K, int lda, int ldb, int ldc, int relu)
{
    __shared__ __align__(16) u16 As[BM * 64];
    __shared__ __align__(16) u16 Bs[BN * 64];

    const int tid = threadIdx.x;
    const int m0 = blockIdx.y * BM, n0 = blockIdx.x * BN;
    const int lane = tid & 63, wid = tid >> 6;
    const int wm = (wid >> 1) * 64, wn = (wid & 1) * 64;
    const int l31 = lane & 31, half = lane >> 5;

    v16f acc[4];
#pragma unroll
    for (int t = 0; t < 4; t++)
#pragma unroll
        for (int r = 0; r < 16; r++) acc[t][r] = 0.f;

    kloop_3232<BM, BN>(A, Bw, K, lda, ldb, As, Bs, tid, m0, n0, wm, wn, l31, half, acc);

#pragma unroll
    for (int mi = 0; mi < 2; mi++)
#pragma unroll
        for (int ni = 0; ni < 2; ni++) {
            const int col = n0 + wn + ni * 32 + l31;
            const float bv = bias[col];
#pragma unroll
            for (int r = 0; r < 16; r++) {
                const int row = m0 + wm + mi * 32 + (r & 3) + 8 * (r >> 2) + 4 * half;
                float v = acc[mi * 2 + ni][r] + bv;
                if (relu) v = fmaxf(v, 0.f);
                Cm[(long)row * ldc + col] = f2b(v);
            }
        }
}

// ---- split-K GEMM-BT (fp32 partials), 32x32 MFMA. N=512, M=4096. ----
template<int BM, int BN>
__global__ __launch_bounds__(256, 2)
void gemm_sk(const u16* __restrict__ A, const u16* __restrict__ Bw,
             float* __restrict__ Pp, int lda, int ldb, int kslice)
{
    __shared__ __align__(16) u16 As[BM * 64];
    __shared__ __align__(16) u16 Bs[BN * 64];

    const int tid = threadIdx.x;
    const int m0 = blockIdx.y * BM, n0 = blockIdx.x * BN;
    const int z = blockIdx.z;
    const int lane = tid & 63, wid = tid >> 6;
    const int wm = (wid >> 1) * 64, wn = (wid & 1) * 64;
    const int l31 = lane & 31, half = lane >> 5;

    v16f acc[4];
#pragma unroll
    for (int t = 0; t < 4; t++)
#pragma unroll
        for (int r = 0; r < 16; r++) acc[t][r] = 0.f;

    kloop_3232<BM, BN>(A + z * kslice, Bw + z * kslice, kslice, lda, ldb,
                       As, Bs, tid, m0, n0, wm, wn, l31, half, acc);

    float* Pz = Pp + (long)z * BL_ * Cx;
#pragma unroll
    for (int mi = 0; mi < 2; mi++)
#pragma unroll
        for (int ni = 0; ni < 2; ni++) {
            const int col = n0 + wn + ni * 32 + l31;
#pragma unroll
            for (int r = 0; r < 16; r++) {
                const int row = m0 + wm + mi * 32 + (r & 3) + 8 * (r >> 2) + 4 * half;
                Pz[(long)row * Cx + col] = acc[mi * 2 + ni][r];
            }
        }
}

// ---- combine split-K partials + bias + residual, then LayerNorm ----
template<int SK>
__global__ __launch_bounds__(256)
void combine_ln(const float* __restrict__ Pp, const float* __restrict__ bias,
                const u16* __restrict__ res, u16* __restrict__ outp,
                const float* __restrict__ gg, const float* __restrict__ bb)
{
    const int wid = threadIdx.x >> 6, lane = threadIdx.x & 63;
    const long r = (long)blockIdx.x * 4 + wid;
    const int c0 = lane * 8;

    int4 t = *reinterpret_cast<const int4*>(res + r * Cx + c0);
    const u16* u = reinterpret_cast<const u16*>(&t);
    float x[8];
#pragma unroll
    for (int i = 0; i < 8; i++) x[i] = b2f(u[i]) + bias[c0 + i];
#pragma unroll
    for (int s = 0; s < SK; s++) {
        const float* p = Pp + ((long)s * BL_ + r) * Cx + c0;
        float4 a = *reinterpret_cast<const float4*>(p);
        float4 b = *reinterpret_cast<const float4*>(p + 4);
        x[0] += a.x; x[1] += a.y; x[2] += a.z; x[3] += a.w;
        x[4] += b.x; x[5] += b.y; x[6] += b.z; x[7] += b.w;
    }
    float s1 = 0.f, s2 = 0.f;
#pragma unroll
    for (int i = 0; i < 8; i++) { s1 += x[i]; s2 += x[i] * x[i]; }
#pragma unroll
    for (int o = 32; o > 0; o >>= 1) { s1 += __shfl_xor(s1, o, 64); s2 += __shfl_xor(s2, o, 64); }
    const float mu = s1 * (1.f / Cx);
    const float var = s2 * (1.f / Cx) - mu * mu;
    const float rs = rsqrtf(var + EPSx);
    int4 ot; u16* ou = reinterpret_cast<u16*>(&ot);
#pragma unroll
    for (int i = 0; i < 8; i++)
        ou[i] = f2b((x[i] - mu) * rs * gg[c0 + i] + bb[c0 + i]);
    *reinterpret_cast<int4*>(outp + r * Cx + c0) = ot;
}

// ---- flash attention: no-max softmax, register-staged dbuf K/V (R8) ----
__global__ __launch_bounds__(256, 2)
void flash_attn(const u16* __restrict__ qkv, const u16* __restrict__ vt,
                const float* __restrict__ relk, const float* __restrict__ relv,
                u16* __restrict__ ao)
{
    const int bh = blockIdx.y, b = bh >> 3, h = bh & 7;
    const int q0 = blockIdx.x * 64;
    const int tid = threadIdx.x, lane = tid & 63, w = tid >> 6;
    const int lrow = lane & 15, quad = lane >> 4;
    constexpr int NT = Lx / 64;

    __shared__ __align__(16) u16 Qs[64 * 64];
    __shared__ __align__(16) u16 Ks[2][64 * 64];
    __shared__ __align__(16) u16 Vs[2][64 * 64];
    __shared__ __align__(16) u16 Ps[4][16 * 64];
    __shared__ float rbias[64][9];
    __shared__ float swin[4][16][9];

    const u16* qbase = qkv + (long)b * Lx * C3 + h * Dx;
    const u16* kbase = qbase + Cx;
    const u16* vbase = vt + (long)bh * Dx * Lx;

    stage_sw<64>(qbase + (long)q0 * C3, C3, Qs, tid);
    stage_sw<64>(kbase, C3, Ks[0], tid);
    stage_sw<64>(vbase, Lx, Vs[0], tid);
    for (int i = tid; i < 4 * 16 * 9; i += 256) (&swin[0][0][0])[i] = -1e30f;
    __syncthreads();

    for (int i = tid; i < 64 * 9; i += 256) {
        int r = i / 9, j = i - (i / 9) * 9;
        float d = 0.f;
        for (int dd = 0; dd < 64; dd++)
            d += b2f(Qs[r * 64 + (((dd >> 3) ^ (r & 7)) << 3) + (dd & 7)]) * relk[j * 64 + dd];
        rbias[r][j] = d;
    }
    __syncthreads();

    int srow[2], scol[2];
#pragma unroll
    for (int i = 0; i < 2; i++) {
        int g = tid + i * 256;
        srow[i] = g >> 3;
        scol[i] = ((g & 7) ^ (srow[i] & 7)) * 8;
    }

    v4f out[4], sfr[4];
    float lpart[4] = {0.f, 0.f, 0.f, 0.f};
#pragma unroll
    for (int nt = 0; nt < 4; nt++) out[nt] = v4f{0.f, 0.f, 0.f, 0.f};

    v8bf aq0 = *reinterpret_cast<const v8bf*>(&Qs[swaddr(w * 16 + lrow, quad)]);
    v8bf aq1 = *reinterpret_cast<const v8bf*>(&Qs[swaddr(w * 16 + lrow, 4 + quad)]);
    const int qw0 = q0 + w * 16;

    for (int kt = 0; kt < NT; kt++) {
        const int k0 = kt * 64;
        const int cur = kt & 1;

        int4 pk[2], pv[2];
        if (kt < NT - 1) {
            const u16* kb2 = kbase + (long)(k0 + 64) * C3;
            const u16* vb2 = vbase + (k0 + 64);
#pragma unroll
            for (int i = 0; i < 2; i++) {
                pk[i] = *reinterpret_cast<const int4*>(kb2 + (long)srow[i] * C3 + scol[i]);
                pv[i] = *reinterpret_cast<const int4*>(vb2 + (long)srow[i] * Lx + scol[i]);
            }
        }

        v8bf bk[2][4], bv[2][4];
#pragma unroll
        for (int ki = 0; ki < 2; ki++)
#pragma unroll
            for (int nt = 0; nt < 4; nt++) {
                bk[ki][nt] = *reinterpret_cast<const v8bf*>(&Ks[cur][swaddr(nt * 16 + lrow, ki * 4 + quad)]);
                bv[ki][nt] = *reinterpret_cast<const v8bf*>(&Vs[cur][swaddr(nt * 16 + lrow, ki * 4 + quad)]);
            }

#pragma unroll
        for (int nt = 0; nt < 4; nt++) sfr[nt] = v4f{0.f, 0.f, 0.f, 0.f};
#pragma unroll
        for (int ki = 0; ki < 2; ki++)
#pragma unroll
            for (int nt = 0; nt < 4; nt++)
                sfr[nt] = __builtin_amdgcn_mfma_f32_16x16x32_bf16(
                    ki ? aq1 : aq0, bk[ki][nt], sfr[nt], 0, 0, 0);

        if (k0 <= qw0 + 15 + WX && k0 + 63 >= qw0 - WX) {
#pragma unroll
            for (int nt = 0; nt < 4; nt++) {
                const int m = k0 + nt * 16 + lrow;
#pragma unroll
                for (int r = 0; r < 4; r++) {
                    const int dj = m - (qw0 + quad * 4 + r);
                    if (dj >= -WX && dj <= WX) {
                        float sv = sfr[nt][r] + rbias[w * 16 + quad * 4 + r][dj + WX];
                        sfr[nt][r] = sv;
                        swin[w][quad * 4 + r][dj + WX] = sv;
                    }
                }
            }
        }

#pragma unroll
        for (int nt = 0; nt < 4; nt++)
#pragma unroll
            for (int r = 0; r < 4; r++) {
                float p = __expf(sfr[nt][r]);
                sfr[nt][r] = p;
                lpart[r] += p;
            }

#pragma unroll
        for (int nt = 0; nt < 4; nt++)
#pragma unroll
            for (int r = 0; r < 4; r++) {
                const int prow = quad * 4 + r;
                Ps[w][prow * 64 + (((nt * 2 + (lrow >> 3)) ^ (prow & 7)) << 3) + (lrow & 7)]
                    = f2b(sfr[nt][r]);
            }

        v8bf pa0 = *reinterpret_cast<const v8bf*>(&Ps[w][swaddr(lrow, quad)]);
        v8bf pa1 = *reinterpret_cast<const v8bf*>(&Ps[w][swaddr(lrow, 4 + quad)]);
#pragma unroll
        for (int nt = 0; nt < 4; nt++) {
            out[nt] = __builtin_amdgcn_mfma_f32_16x16x32_bf16(pa0, bv[0][nt], out[nt], 0, 0, 0);
            out[nt] = __builtin_amdgcn_mfma_f32_16x16x32_bf16(pa1, bv[1][nt], out[nt], 0, 0, 0);
        }

        if (kt < NT - 1) {
            u16* Kn = Ks[cur ^ 1];
            u16* Vn = Vs[cur ^ 1];
#pragma unroll
            for (int i = 0; i < 2; i++) {
                *reinterpret_cast<int4*>(Kn + (tid + i * 256) * 8) = pk[i];
                *reinterpret_cast<int4*>(Vn + (tid + i * 256) * 8) = pv[i];
            }
        }
        __syncthreads();
    }

#pragma unroll
    for (int off = 1; off < 16; off <<= 1)
#pragma unroll
        for (int r = 0; r < 4; r++) lpart[r] += __shfl_xor(lpart[r], off, 64);
    float inv[4];
#pragma unroll
    for (int r = 0; r < 4; r++) inv[r] = 1.f / lpart[r];

    float e[4][9];
#pragma unroll
    for (int r = 0; r < 4; r++)
#pragma unroll
        for (int j = 0; j < 9; j++) e[r][j] = __expf(swin[w][quad * 4 + r][j]);
#pragma unroll
    for (int nt = 0; nt < 4; nt++) {
        const int d = nt * 16 + lrow;
#pragma unroll
        for (int r = 0; r < 4; r++) {
            float a = out[nt][r];
#pragma unroll
            for (int j = 0; j < 9; j++) a += e[r][j] * relv[j * 64 + d];
            ao[((long)(b * Lx + qw0 + quad * 4 + r)) * Cx + h * Dx + d] = f2b(a * inv[r]);
        }
    }
}

// ---- transpose with dtype conversion ----
template<typename TI, typename TO>
__global__ __launch_bounds__(256)
void transpose_k(const TI* __restrict__ in, TO* __restrict__ outp,
                 int ld_in, int ld_out, int zdiv,
                 long si1, long si2, long so1, long so2)
{
    const int z = blockIdx.z;
    in   += (z / zdiv) * si1 + (z % zdiv) * si2;
    outp += (z / zdiv) * so1 + (z % zdiv) * so2;
    const int r0 = blockIdx.y * 32, c0 = blockIdx.x * 32;
    __shared__ float t[32][33];
    const int tid = threadIdx.x;
    const int lr = tid >> 3, lc = (tid & 7) * 4;
#pragma unroll
    for (int j = 0; j < 4; j++)
        t[lr][lc + j] = ldf(in + (long)(r0 + lr) * ld_in + (c0 + lc + j));
    __syncthreads();
#pragma unroll
    for (int j = 0; j < 4; j++)
        stf(outp + (long)(c0 + lr) * ld_out + (r0 + lc + j), t[lc + j][lr]);
}

extern "C" void kernel_launch(void* const* d_in, const int* in_sizes, int n_in,
                              void* d_out, int out_size, void* d_ws, size_t ws_size,
                              hipStream_t stream)
{
    const float* x   = (const float*)d_in[0];
    const float* wq  = (const float*)d_in[2];
    const float* bq  = (const float*)d_in[3];
    const float* wk  = (const float*)d_in[4];
    const float* bk  = (const float*)d_in[5];
    const float* wv  = (const float*)d_in[6];
    const float* bv  = (const float*)d_in[7];
    const float* wo  = (const float*)d_in[8];
    const float* bo  = (const float*)d_in[9];
    const float* rk  = (const float*)d_in[10];
    const float* rv  = (const float*)d_in[11];
    const float* l1g = (const float*)d_in[12];
    const float* l1b = (const float*)d_in[13];
    const float* w1  = (const float*)d_in[14];
    const float* b1  = (const float*)d_in[15];
    const float* w2  = (const float*)d_in[16];
    const float* b2  = (const float*)d_in[17];
    const float* l2g = (const float*)d_in[18];
    const float* l2b = (const float*)d_in[19];
    float* out = (float*)d_out;

    const long BL = (long)BL_;
    char* wp = (char*)d_ws;
    auto carveB = [&](long bytes) -> char* {
        char* p = wp;
        wp += ((bytes + 255) & ~255L);
        return p;
    };
    u16* xt    = (u16*)carveB(BL * Cx * 2);
    u16* qkv   = (u16*)carveB(BL * C3 * 2);
    u16* vt    = (u16*)carveB(BL * Cx * 2);
    u16* ao    = (u16*)carveB(BL * Cx * 2);
    u16* x2    = (u16*)carveB(BL * Cx * 2);
    u16* h1    = (u16*)carveB(BL * FCx * 2);
    u16* wqkvb = (u16*)carveB((long)NLx * C3 * Cx * 2);
    u16* wob   = (u16*)carveB((long)NLx * Cx * Cx * 2);
    u16* w1b   = (u16*)carveB((long)NLx * FCx * Cx * 2);
    u16* w2b   = (u16*)carveB((long)NLx * Cx * FCx * 2);
    float* bqkvf = (float*)carveB((long)NLx * C3 * 4);
    float* pp    = (float*)carveB((long)4 * BL * Cx * 4);   // 32 MB split-K partials

    const int CC = Cx * Cx;
    const long WL = (long)C3 * Cx;

    pack_all<<<2048, 256, 0, stream>>>(wq, wk, wv, wo, w1, w2, bq, bk, bv,
                                       wqkvb, wob, w1b, w2b, bqkvf);

    transpose_k<float, u16><<<dim3(Lx / 32, Cx / 32, Bx), 256, 0, stream>>>(
        x, xt, Lx, Cx, 1, (long)Cx * Lx, 0, (long)Lx * Cx, 0);

    for (int i = 0; i < NLx; i++) {
        const u16* wqkvi = wqkvb + (long)i * WL;
        const u16* woi   = wob + (long)i * CC;
        const u16* w1i   = w1b + (long)i * FCx * Cx;
        const u16* w2i   = w2b + (long)i * Cx * FCx;
        const float* bqkvi = bqkvf + (long)i * C3;

        // fused QKV projection (128x128 tiles, 384 blocks)
        gemm_bt<128, 128><<<dim3(C3 / 128, BL_ / 128), 256, 0, stream>>>(
            xt, wqkvi, qkv, bqkvi, Cx, Cx, Cx, C3, 0);

        transpose_k<u16, u16><<<dim3(Dx / 32, Lx / 32, Bx * Hx), 256, 0, stream>>>(
            qkv + 2 * Cx, vt, C3, Lx, Hx, (long)Lx * C3, Dx, (long)Hx * Dx * Lx, (long)Dx * Lx);

        flash_attn<<<dim3(Lx / 64, Bx * Hx), 256, 0, stream>>>(
            qkv, vt, rk + i * 9 * Dx, rv + i * 9 * Dx, ao);

        // O-projection: split-K=2, combine + bias + residual(xt) + LN -> x2
        gemm_sk<128, 128><<<dim3(Cx / 128, BL_ / 128, 2), 256, 0, stream>>>(
            ao, woi, pp, Cx, Cx, Cx / 2);
        combine_ln<2><<<dim3(BL_ / 4), 256, 0, stream>>>(
            pp, bo + i * Cx, xt, x2, l1g + i * Cx, l1b + i * Cx);

        // FFN1 (bias+relu)
        gemm_bt<128, 128><<<dim3(FCx / 128, BL_ / 128), 256, 0, stream>>>(
            x2, w1i, h1, b1 + i * FCx, Cx, Cx, Cx, FCx, 1);

        // FFN2: split-K=4, combine + bias + residual(x2) + LN -> xt
        gemm_sk<128, 128><<<dim3(Cx / 128, BL_ / 128, 4), 256, 0, stream>>>(
            h1, w2i, pp, FCx, FCx, FCx / 4);
        combine_ln<4><<<dim3(BL_ / 4), 256, 0, stream>>>(
            pp, b2 + i * Cx, x2, xt, l2g + i * Cx, l2b + i * Cx);
    }

    transpose_k<u16, float><<<dim3(Cx / 32, Lx / 32, Bx), 256, 0, stream>>>(
        xt, out, Cx, Lx, 1, (long)Lx * Cx, 0, (long)Cx * Lx, 0);
}